// Round 2
// 3905.870 us; speedup vs baseline: 2.0132x; 2.0132x over previous
//
#include <hip/hip_runtime.h>

#define B_ 128
#define T_ 512
#define I_ 512
#define H_ 1024
#define G3_ 3072

typedef _Float16 half8 __attribute__((ext_vector_type(8)));
typedef float f32x4 __attribute__((ext_vector_type(4)));
typedef float f32x2 __attribute__((ext_vector_type(2)));

// LDS: wh[3][32][64] half8 (96K) | wi[3][16][64] half8 (48K) |
//      f32 partials r[2][512], z[2][512], nh[2][512], nin[512] (14K)
#define SMEM_WH_OFF 0
#define SMEM_WI_OFF 98304
#define SMEM_F_OFF  147456
#define SMEM_BYTES  (147456 + 14336)   // 161792 <= 160 KiB

#define MFMA16(a, b, c) __builtin_amdgcn_mfma_f32_16x16x32_f16((a), (b), (c), 0, 0, 0)

// Device-coherent 16B load: 2x 8B agent-scope relaxed atomic loads.
// Bypasses L1/L2 (reads the coherence point directly) -> no per-step
// buffer_inv needed, and L2 keeps the Xt stream warm across steps.
__device__ __forceinline__ half8 ldg_h8_agent(const half8* p) {
  union { unsigned long long d[2]; half8 v; } u;
  const unsigned long long* q = (const unsigned long long*)p;
  u.d[0] = __hip_atomic_load(q,     __ATOMIC_RELAXED, __HIP_MEMORY_SCOPE_AGENT);
  u.d[1] = __hip_atomic_load(q + 1, __ATOMIC_RELAXED, __HIP_MEMORY_SCOPE_AGENT);
  return u.v;
}

// ---------------- prep kernels ----------------

// X (B,T,I) fp32 -> Xt (T,B,I) fp16
__global__ void prep_xt(const float* __restrict__ X, _Float16* __restrict__ Xt) {
  size_t o = (size_t)blockIdx.x * 256 + threadIdx.x;   // total B*T*I = 2^25
  int i = (int)(o & (I_ - 1));
  int b = (int)((o >> 9) & (B_ - 1));
  int t = (int)(o >> 16);
  Xt[o] = (_Float16)X[((size_t)b * T_ + t) * I_ + i];
}

// W (K,3072) fp32 row-major -> MFMA B-fragment swizzled fp16
__global__ void prep_wsw(const float* __restrict__ W, _Float16* __restrict__ Wsw, int ktiles) {
  size_t e = (size_t)blockIdx.x * 256 + threadIdx.x;
  int per_nt = ktiles * 512;
  int nt = (int)(e / per_nt);
  int rem = (int)(e % per_nt);
  int kt = rem >> 9;
  int l = (rem >> 3) & 63;
  int j = rem & 7;
  int k = kt * 32 + (l >> 4) * 8 + j;
  int n = nt * 16 + (l & 15);
  Wsw[e] = (_Float16)W[(size_t)k * G3_ + n];
}

// zero both h-state buffers + flag slots
__global__ void prep_zero(_Float16* __restrict__ h16, unsigned int* __restrict__ ctr) {
  int o = blockIdx.x * 256 + threadIdx.x;  // grid covers 2*B_*H_ elems
  h16[o] = (_Float16)0.f;
  if (o < 8192) ctr[o] = 0u;               // 4 groups * 64 slots * 32 uints
}

// ---------------- main persistent scan kernel ----------------
// grid = 256 blocks: gb = bid>>6 (32 batch rows), gn = bid&63 (16 h-cols)
// block = 256 threads = 4 waves: wave w -> mi = w&1 (16-row m-tile), ks = w>>1 (K half)
// Each wave computes ALL 3 gates for its (mi, K-half) -> A fragments loaded once.
//
// Sync protocol (per step, ZERO cache-maintenance ops on the critical path):
//   producer: h16 stores are sc0sc1 write-through (agent relaxed atomics);
//             __syncthreads drains vmcnt(0) -> all h stores ACKED at the
//             coherence point; THEN tid0 issues the flag store (relaxed is
//             sufficient: issue-after-ack order is preserved per-wave).
//   consumer: polls flags (agent relaxed loads), then reads h16 A-fragments
//             with agent relaxed atomic loads (L1/L2-bypassing). No
//             buffer_wbl2, no buffer_inv anywhere in the loop.
__global__ void __launch_bounds__(256, 1) gru_scan(
    const _Float16* __restrict__ Xt,
    const _Float16* __restrict__ Whs,
    const _Float16* __restrict__ Wis,
    _Float16* __restrict__ h16,      // [2][B_][H_] double-buffered state
    const float* __restrict__ bias,  // 6H
    float* __restrict__ out,         // hseq (B,T,H) fp32 then h_last (B,H)
    unsigned int* __restrict__ ctr)  // flags: [(gb*64+gn)*32], 128B-padded slots
{
  extern __shared__ char smem[];
  half8* lds_wh = (half8*)(smem + SMEM_WH_OFF);   // [3][32][64]
  half8* lds_wi = (half8*)(smem + SMEM_WI_OFF);   // [3][16][64]
  float* s_r   = (float*)(smem + SMEM_F_OFF);     // [2][512]
  float* s_z   = s_r + 1024;                      // [2][512]
  float* s_nh  = s_z + 1024;                      // [2][512]
  float* s_nin = s_nh + 1024;                     // [512]

  const int bid = blockIdx.x;
  const int gb = bid >> 6;
  const int gn = bid & 63;
  const int tid = threadIdx.x;
  const int lane = tid & 63;
  const int w = tid >> 6;
  const int mi = w & 1;
  const int ks = w >> 1;

  const int r0 = gb * 32;
  const int c0 = gn * 16;

  // ---- stage weights into LDS (once) ----
  const half8* Whs8 = (const half8*)Whs;
  const half8* Wis8 = (const half8*)Wis;
  for (int e = tid; e < 6144; e += 256) {
    int gg = e >> 11, rest = e & 2047;
    lds_wh[e] = Whs8[(size_t)(gg * 64 + gn) * 2048 + rest];
  }
  for (int e = tid; e < 3072; e += 256) {
    int gg = e >> 10, rest = e & 1023;
    lds_wi[e] = Wis8[(size_t)(gg * 64 + gn) * 1024 + rest];
  }

  // per-thread elementwise ownership: row = tid>>3, two adjacent cols (tid&7)*2
  const int erow = tid >> 3;
  const int ecp = (tid & 7) * 2;
  float br[2], bz[2], bin[2], bhn[2], hreg[2] = {0.f, 0.f};
  #pragma unroll
  for (int e = 0; e < 2; ++e) {
    const int cg = c0 + ecp + e;
    br[e]  = bias[cg]           + bias[G3_ + cg];
    bz[e]  = bias[H_ + cg]      + bias[G3_ + H_ + cg];
    bin[e] = bias[2 * H_ + cg];
    bhn[e] = bias[G3_ + 2 * H_ + cg];
  }

  const int am = lane & 15;        // A row within 16-tile / C col
  const int aq = lane >> 4;        // k-quad
  const int arow = r0 + mi * 16 + am;
  const half8* Ah_base = (const half8*)h16 + (size_t)arow * (H_ / 8) + aq;
  const int HB8 = B_ * H_ / 8;

  __syncthreads();

  // ---- input GEMM for t=0 (r,z split by K-half as MFMA C-init; n full-K on ks==0) ----
  f32x4 acc_ir = {0.f,0.f,0.f,0.f}, acc_iz = {0.f,0.f,0.f,0.f}, acc_in = {0.f,0.f,0.f,0.f};
  {
    const half8* Ax = (const half8*)Xt + (size_t)arow * (I_ / 8) + aq;
    #pragma unroll
    for (int j = 0; j < 8; ++j) {
      const int k = ks * 8 + j;
      half8 a = Ax[k * 4];
      acc_ir = MFMA16(a, lds_wi[k * 64 + lane], acc_ir);
      acc_iz = MFMA16(a, lds_wi[(16 + k) * 64 + lane], acc_iz);
    }
    if (ks == 0) {
      #pragma unroll
      for (int k = 0; k < 16; ++k)
        acc_in = MFMA16(Ax[k * 4], lds_wi[(32 + k) * 64 + lane], acc_in);
    }
  }

  for (int t = 0; t < T_; ++t) {
    const int p = t & 1;
    const bool last = (t == T_ - 1);

    // ---- recurrent GEMM: A loaded once into regs (coherent loads), reused for 3 gates ----
    const half8* Ah = Ah_base + (size_t)p * HB8;
    half8 a[16];
    #pragma unroll
    for (int j = 0; j < 16; ++j) a[j] = ldg_h8_agent(Ah + (ks * 16 + j) * 4);
    f32x4 ar = acc_ir, az = acc_iz, an = {0.f,0.f,0.f,0.f};
    #pragma unroll
    for (int j = 0; j < 16; ++j) {
      const int k = ks * 16 + j;
      ar = MFMA16(a[j], lds_wh[k * 64 + lane], ar);
      az = MFMA16(a[j], lds_wh[(32 + k) * 64 + lane], az);
      an = MFMA16(a[j], lds_wh[(64 + k) * 64 + lane], an);
    }

    // C/D layout: col = lane&15, row = (lane>>4)*4 + q
    const int rowb = mi * 16 + aq * 4;
    #pragma unroll
    for (int q = 0; q < 4; ++q) {
      s_r[ks * 512 + (rowb + q) * 16 + am]  = ar[q];
      s_z[ks * 512 + (rowb + q) * 16 + am]  = az[q];
      s_nh[ks * 512 + (rowb + q) * 16 + am] = an[q];
    }
    if (ks == 0) {
      #pragma unroll
      for (int q = 0; q < 4; ++q) s_nin[(rowb + q) * 16 + am] = acc_in[q];
    }
    __syncthreads();

    // ---- elementwise GRU update (h master in regs) ----
    float hn[2];
    #pragma unroll
    for (int e = 0; e < 2; ++e) {
      const int idx = erow * 16 + ecp + e;
      const float rp = s_r[idx] + s_r[512 + idx] + br[e];
      const float zp = s_z[idx] + s_z[512 + idx] + bz[e];
      const float rr = 1.f / (1.f + __expf(-rp));
      const float zz = 1.f / (1.f + __expf(-zp));
      const float np = s_nin[idx] + bin[e] + rr * (s_nh[idx] + s_nh[512 + idx] + bhn[e]);
      const float nn = 1.f - 2.f / (__expf(2.f * np) + 1.f);   // tanh
      hn[e] = (1.f - zz) * nn + zz * hreg[e];
      hreg[e] = hn[e];
    }
    if (!last) {
      // device-coherent write-through store (no L2 dirty state, no wbl2 needed)
      _Float16* hw = h16 + (size_t)(1 - p) * (B_ * H_);
      union { _Float16 h[2]; unsigned u; } pk;
      pk.h[0] = (_Float16)hn[0]; pk.h[1] = (_Float16)hn[1];
      __hip_atomic_store((unsigned*)(hw + (size_t)(r0 + erow) * H_ + c0 + ecp), pk.u,
                         __ATOMIC_RELAXED, __HIP_MEMORY_SCOPE_AGENT);
    }
    __syncthreads();   // every wave drains vmcnt(0): all h16 stores acked at coherence point

    if (!last) {
      // ---- signal: own padded flag slot. RELAXED is sufficient: the
      // preceding __syncthreads drained vmcnt(0), so every h16 store in this
      // block is already acked at the coherence point before this store
      // issues. No RELEASE -> no buffer_wbl2 sc1 on the critical path.
      if (tid == 0)
        __hip_atomic_store(ctr + (size_t)(gb * 64 + gn) * 32, (unsigned)(t + 1),
                           __ATOMIC_RELAXED, __HIP_MEMORY_SCOPE_AGENT);

      // ---- barrier shadow: out stores + next-step input GEMM ----
      {
        f32x2 v; v[0] = hn[0]; v[1] = hn[1];
        __builtin_nontemporal_store(v,
            (f32x2*)(out + ((size_t)(r0 + erow) * T_ + t) * H_ + c0 + ecp));
      }

      acc_ir = (f32x4){0.f,0.f,0.f,0.f};
      acc_iz = (f32x4){0.f,0.f,0.f,0.f};
      acc_in = (f32x4){0.f,0.f,0.f,0.f};
      const half8* Ax = (const half8*)Xt + ((size_t)(t + 1) * B_ + arow) * (I_ / 8) + aq;
      #pragma unroll
      for (int j = 0; j < 8; ++j) {
        const int k = ks * 8 + j;
        half8 ax = Ax[k * 4];
        acc_ir = MFMA16(ax, lds_wi[k * 64 + lane], acc_ir);
        acc_iz = MFMA16(ax, lds_wi[(16 + k) * 64 + lane], acc_iz);
      }
      if (ks == 0) {
        #pragma unroll
        for (int k = 0; k < 16; ++k)
          acc_in = MFMA16(Ax[k * 4], lds_wi[(32 + k) * 64 + lane], acc_in);
      }

      // ---- wait: wave 0 watches all 64 flags in parallel ----
      if (w == 0) {
        const unsigned tgt = (unsigned)(t + 1);
        const unsigned* fp = ctr + (size_t)(gb * 64 + lane) * 32;
        unsigned v = 0;
        bool done = false;
        while (true) {
          if (!done) {
            v = __hip_atomic_load(fp, __ATOMIC_RELAXED, __HIP_MEMORY_SCOPE_AGENT);
            done = (v >= tgt);
          }
          if (__all((int)done)) break;
          __builtin_amdgcn_s_sleep(1);
        }
      }
      __syncthreads();
      // NOTE: no acquire fence here. h16 A-fragment loads at the top of the
      // next iteration are agent-scope atomic loads that bypass L1/L2, so
      // freshness is per-load; L2 keeps Xt warm across steps.
    } else {
      // final step: hseq[t] + h_last
      f32x2 v; v[0] = hn[0]; v[1] = hn[1];
      __builtin_nontemporal_store(v,
          (f32x2*)(out + ((size_t)(r0 + erow) * T_ + t) * H_ + c0 + ecp));
      __builtin_nontemporal_store(v,
          (f32x2*)(out + (size_t)B_ * T_ * H_ + (size_t)(r0 + erow) * H_ + c0 + ecp));
    }
  }
}

// ---------------- launcher ----------------
extern "C" void kernel_launch(void* const* d_in, const int* in_sizes, int n_in,
                              void* d_out, int out_size, void* d_ws, size_t ws_size,
                              hipStream_t stream) {
  const float* X    = (const float*)d_in[0];   // (B,T,I)
  const float* Win  = (const float*)d_in[1];   // (I,3H)
  const float* Wh   = (const float*)d_in[2];   // (H,3H)
  const float* bias = (const float*)d_in[3];   // (6H)
  float* out = (float*)d_out;

  // workspace layout
  const size_t OFF_XT  = 0;                          // 512*128*512*2 = 67,108,864
  const size_t OFF_WHS = 67108864;                   // 1024*3072*2  =  6,291,456
  const size_t OFF_WIS = 73400320;                   // 512*3072*2   =  3,145,728
  const size_t OFF_H16 = 76546048;                   // 2*128*1024*2 =    524,288
  const size_t OFF_CTR = 77070336;                   // 4*64 slots * 128B = 32,768
  const size_t NEEDED  = OFF_CTR + 32768;
  if (ws_size < NEEDED) return;  // workspace too small — fail visibly

  char* ws = (char*)d_ws;
  _Float16* Xt  = (_Float16*)(ws + OFF_XT);
  _Float16* Whs = (_Float16*)(ws + OFF_WHS);
  _Float16* Wis = (_Float16*)(ws + OFF_WIS);
  _Float16* h16 = (_Float16*)(ws + OFF_H16);
  unsigned int* ctr = (unsigned int*)(ws + OFF_CTR);

  hipFuncSetAttribute((const void*)gru_scan,
                      hipFuncAttributeMaxDynamicSharedMemorySize, SMEM_BYTES);

  prep_xt<<<dim3(131072), dim3(256), 0, stream>>>(X, Xt);
  prep_wsw<<<dim3(12288), dim3(256), 0, stream>>>(Wh, Whs, 32);   // 192 nt * 32 kt
  prep_wsw<<<dim3(6144),  dim3(256), 0, stream>>>(Win, Wis, 16);  // 192 nt * 16 kt
  prep_zero<<<dim3(1024), dim3(256), 0, stream>>>(h16, ctr);

  void* args[] = { (void*)&Xt, (void*)&Whs, (void*)&Wis, (void*)&h16,
                   (void*)&bias, (void*)&out, (void*)&ctr };
  hipLaunchCooperativeKernel((void*)gru_scan, dim3(256), dim3(256), args,
                             SMEM_BYTES, stream);
}